// Round 4
// baseline (1191.172 us; speedup 1.0000x reference)
//
#include <hip/hip_runtime.h>
#include <hip/hip_bf16.h>

typedef _Float16 f16;
typedef _Float16 f16x4 __attribute__((ext_vector_type(4)));
typedef _Float16 f16x8 __attribute__((ext_vector_type(8)));
typedef float f32x4 __attribute__((ext_vector_type(4)));

__device__ __forceinline__ void gload16(const void* g, void* l) {
    __builtin_amdgcn_global_load_lds(
        (const __attribute__((address_space(1))) void*)g,
        (__attribute__((address_space(3))) void*)l, 16, 0, 0);
}

// ---------------------------------------------------------------------------
// BT-GEMM (unchanged from r2): C[m][n] = sum_k A[m][k]*B[n][k], fp32 in, f16 out.
// ---------------------------------------------------------------------------
__global__ __launch_bounds__(256) void proj_gemm(
    const float* __restrict__ A, const float* __restrict__ B,
    f16* __restrict__ C, int ldc)
{
    constexpr int K = 1024, BK = 64;
    __shared__ f16 sA[128 * BK];
    __shared__ f16 sB[128 * BK];
    const int tid = threadIdx.x;
    const int lane = tid & 63, wid = tid >> 6;
    const int wr = wid >> 1, wc = wid & 1;
    const int bm = blockIdx.x * 128, bn = blockIdx.y * 128;

    f32x4 acc[4][4] = {};

    for (int kt = 0; kt < K; kt += BK) {
        __syncthreads();
        {
            const int r0 = tid >> 4;
            const int c4 = (tid & 15) << 2;
#pragma unroll
            for (int p = 0; p < 8; ++p) {
                const int row = (p << 4) + r0;
                const float4 av = *(const float4*)(A + (size_t)(bm + row) * K + kt + c4);
                const float4 bv = *(const float4*)(B + (size_t)(bn + row) * K + kt + c4);
                const int sc = c4 ^ ((row & 7) << 3);
                f16x4 ah = { (f16)av.x, (f16)av.y, (f16)av.z, (f16)av.w };
                f16x4 bh = { (f16)bv.x, (f16)bv.y, (f16)bv.z, (f16)bv.w };
                *(f16x4*)(&sA[(row << 6) + sc]) = ah;
                *(f16x4*)(&sB[(row << 6) + sc]) = bh;
            }
        }
        __syncthreads();
#pragma unroll
        for (int ks = 0; ks < 2; ++ks) {
            const int kk = ks * 32 + (lane >> 4) * 8;
            f16x8 a[4], b[4];
#pragma unroll
            for (int i = 0; i < 4; ++i) {
                const int ra = wr * 64 + i * 16 + (lane & 15);
                a[i] = *(const f16x8*)(&sA[(ra << 6) + (kk ^ ((ra & 7) << 3))]);
                const int rb = wc * 64 + i * 16 + (lane & 15);
                b[i] = *(const f16x8*)(&sB[(rb << 6) + (kk ^ ((rb & 7) << 3))]);
            }
#pragma unroll
            for (int i = 0; i < 4; ++i)
#pragma unroll
                for (int j = 0; j < 4; ++j)
                    acc[i][j] = __builtin_amdgcn_mfma_f32_16x16x32_f16(a[i], b[j], acc[i][j], 0, 0, 0);
        }
    }
#pragma unroll
    for (int i = 0; i < 4; ++i)
#pragma unroll
        for (int j = 0; j < 4; ++j)
#pragma unroll
            for (int r = 0; r < 4; ++r) {
                const int row = bm + wr * 64 + i * 16 + (lane >> 4) * 4 + r;
                const int col = bn + wc * 64 + j * 16 + (lane & 15);
                C[(size_t)row * ldc + col] = (f16)acc[i][j][r];
            }
}

// ---------------------------------------------------------------------------
// Flash attention v2 (r3 + batch-offset fix): Bk=128, global_load_lds dbuf
// staging (pre-swizzled global source, linear LDS dest), swizzled sS.
// Q interleaved in d_out (row stride 2048 halfs); Q/out alias -> no restrict.
// ---------------------------------------------------------------------------
__global__ __launch_bounds__(512, 2) void flash_attn(
    const f16* Q, const f16* __restrict__ Km,
    const f16* __restrict__ VT, float* out)
{
    constexpr int D = 1024, N = 4096, Bq = 64, Bk = 128, DC = 128, NT = N / Bk;
    constexpr int QSTR = 2048;
    __shared__ f16 sQ[2][Bq * DC];      // 2 x 16 KB
    __shared__ f16 sK[2][Bk * DC];      // 2 x 32 KB
    __shared__ float sS[Bq * Bk];       // 32 KB
    __shared__ f16 sP[Bq * Bk];         // 16 KB
    __shared__ float sm[Bq], sl[Bq], sscale[Bq];

    const int tid = threadIdx.x, lane = tid & 63, wid = tid >> 6;
    // XCD-grouped mapping: 2 XCDs per batch (blocks round-robin XCDs by index)
    const int bi = blockIdx.x;
    const int xcd = bi & 7;
    const int b = xcd >> 1;
    const int qb = ((bi >> 3) << 1) | (xcd & 1);

    const size_t kbase = (size_t)b * N * D;   // halfs
    const size_t vtok = (size_t)b * N;        // token base into VT rows

    // --- staging constants: lane l writes LDS linear half-offset l*8 within its
    // 1KB segment (4 rows x 128 halfs); source col pre-swizzled so reads can use
    // col ^ ((row&7)<<3). Segment parity is wave-uniform for both Q and K sets.
    const int lq = lane >> 4;
    const int swv = ((((wid & 1) << 2) | lq) & 7) << 3;
    const int colsw = ((lane & 15) << 3) ^ swv;
    const size_t qrow0 = (size_t)b * N + (size_t)qb * Bq;   // token index of q row 0
    const size_t qoff0 = (qrow0 + wid * 4 + lq) * QSTR + colsw;
    const size_t qoff1 = (qrow0 + (wid + 8) * 4 + lq) * QSTR + colsw;
    const size_t koff0 = kbase + (size_t)(wid * 4 + lq) * D + colsw;

    if (tid < Bq) { sm[tid] = -1e30f; sl[tid] = 0.0f; }

    f32x4 acc[4][8] = {};
    const int qf = wid & 3, kh = wid >> 2;

    auto stage = [&](int ci) {
        const int kt2 = ci >> 3, dc2 = ci & 7, bsel = ci & 1;
        const int dco = dc2 << 7;                       // halfs
        f16* qd = &sQ[bsel][wid << 9];
        gload16(Q + qoff0 + dco, qd);
        gload16(Q + qoff1 + dco, qd + 4096);
        const size_t kof = koff0 + ((size_t)kt2 << 17) + dco;
        f16* kd = &sK[bsel][wid << 9];
        gload16(Km + kof,          kd);
        gload16(Km + kof + 32768,  kd + 4096);
        gload16(Km + kof + 65536,  kd + 8192);
        gload16(Km + kof + 98304,  kd + 12288);
    };

    stage(0);
    __syncthreads();

    for (int kt = 0; kt < NT; ++kt) {
        f32x4 accs[4] = {};
        // ---- QK^T over 8 d-chunks, double-buffered async staging ----
        for (int dc = 0; dc < 8; ++dc) {
            const int ci = kt * 8 + dc;
            if (ci + 1 < NT * 8) stage(ci + 1);
            const f16* bq = sQ[dc & 1];
            const f16* bk = sK[dc & 1];
#pragma unroll
            for (int ks = 0; ks < 4; ++ks) {
                const int kk = ks * 32 + (lane >> 4) * 8;
                const int ra = qf * 16 + (lane & 15);
                f16x8 a = *(const f16x8*)(bq + ra * DC + (kk ^ ((ra & 7) << 3)));
#pragma unroll
                for (int f = 0; f < 4; ++f) {
                    const int rb = (kh * 4 + f) * 16 + (lane & 15);
                    f16x8 bb = *(const f16x8*)(bk + rb * DC + (kk ^ ((rb & 7) << 3)));
                    accs[f] = __builtin_amdgcn_mfma_f32_16x16x32_f16(a, bb, accs[f], 0, 0, 0);
                }
            }
            if (dc < 7) __syncthreads();
        }
        // ---- write S tile (swizzled: rows stride 4 here -> use (row>>2)&7) ----
#pragma unroll
        for (int f = 0; f < 4; ++f)
#pragma unroll
            for (int r = 0; r < 4; ++r) {
                const int row = qf * 16 + (lane >> 4) * 4 + r;
                const int col = (kh * 4 + f) * 16 + (lane & 15);
                sS[row * Bk + (col ^ (((row >> 2) & 7) << 3))] = accs[f][r];
            }
        __syncthreads();
        // ---- online softmax: wave owns rows wid*8..+8, 8 lanes/row, 16 cols ----
        {
            const int row = wid * 8 + (lane >> 3);
            const int c0 = (lane & 7) << 4;
            const int sw32 = ((row >> 2) & 7) << 3;
            float v[16];
#pragma unroll
            for (int u = 0; u < 4; ++u) {
                float4 t = *(const float4*)(&sS[row * Bk + ((c0 + u * 4) ^ sw32)]);
                v[u * 4 + 0] = t.x; v[u * 4 + 1] = t.y; v[u * 4 + 2] = t.z; v[u * 4 + 3] = t.w;
            }
            float tmax = v[0];
#pragma unroll
            for (int j = 1; j < 16; ++j) tmax = fmaxf(tmax, v[j]);
#pragma unroll
            for (int m = 1; m <= 4; m <<= 1) tmax = fmaxf(tmax, __shfl_xor(tmax, m));
            const float mold = sm[row];
            const float mnew = fmaxf(mold, tmax);
            float ps = 0.f;
#pragma unroll
            for (int j = 0; j < 16; ++j) { v[j] = __expf(v[j] - mnew); ps += v[j]; }
#pragma unroll
            for (int m = 1; m <= 4; m <<= 1) ps += __shfl_xor(ps, m);
            const float scl = __expf(mold - mnew);
            if ((lane & 7) == 0) {
                sm[row] = mnew;
                sl[row] = sl[row] * scl + ps;
                sscale[row] = scl;
            }
            const int swh = (row & 7) << 3;
            f16x8 p0, p1;
#pragma unroll
            for (int j = 0; j < 8; ++j) { p0[j] = (f16)v[j]; p1[j] = (f16)v[8 + j]; }
            *(f16x8*)(&sP[row * Bk + (c0 ^ swh)]) = p0;
            *(f16x8*)(&sP[row * Bk + ((c0 + 8) ^ swh)]) = p1;
        }
        __syncthreads();
        // ---- rescale accumulator + PV ----
        float scl4[4][4];
#pragma unroll
        for (int i = 0; i < 4; ++i)
#pragma unroll
            for (int r = 0; r < 4; ++r)
                scl4[i][r] = sscale[i * 16 + (lane >> 4) * 4 + r];
#pragma unroll
        for (int i = 0; i < 4; ++i)
#pragma unroll
            for (int j = 0; j < 8; ++j)
#pragma unroll
                for (int r = 0; r < 4; ++r) acc[i][j][r] *= scl4[i][r];
        const size_t tok0 = vtok + (size_t)kt * Bk;
#pragma unroll
        for (int ks = 0; ks < 4; ++ks) {
            const int kk = ks * 32 + (lane >> 4) * 8;
            f16x8 a[4];
#pragma unroll
            for (int i = 0; i < 4; ++i) {
                const int ra = i * 16 + (lane & 15);
                a[i] = *(const f16x8*)(&sP[ra * Bk + (kk ^ ((ra & 7) << 3))]);
            }
#pragma unroll
            for (int j = 0; j < 8; ++j) {
                const int dcol = wid * 128 + j * 16 + (lane & 15);
                const f16x8 bb = *(const f16x8*)(VT + (size_t)dcol * 16384 + tok0 + kk);
#pragma unroll
                for (int i = 0; i < 4; ++i)
                    acc[i][j] = __builtin_amdgcn_mfma_f32_16x16x32_f16(a[i], bb, acc[i][j], 0, 0, 0);
            }
        }
        // no end-of-tile barrier needed: next writes to sP/sS are >2 barriers away
    }
    // ---- epilogue: att = acc / (32 * l) ----
#pragma unroll
    for (int i = 0; i < 4; ++i) {
        float inv[4];
#pragma unroll
        for (int r = 0; r < 4; ++r)
            inv[r] = 1.0f / (sl[i * 16 + (lane >> 4) * 4 + r] * 32.0f);
#pragma unroll
        for (int j = 0; j < 8; ++j) {
            const int dcol = wid * 128 + j * 16 + (lane & 15);
#pragma unroll
            for (int r = 0; r < 4; ++r) {
                const int row = i * 16 + (lane >> 4) * 4 + r;
                out[((size_t)b * N + (size_t)qb * Bq + row) * D + dcol] = acc[i][j][r] * inv[r];
            }
        }
    }
}

extern "C" void kernel_launch(void* const* d_in, const int* in_sizes, int n_in,
                              void* d_out, int out_size, void* d_ws, size_t ws_size,
                              hipStream_t stream) {
    const float* x  = (const float*)d_in[0];   // [4,4096,1024]
    const float* Wq = (const float*)d_in[1];   // [1024,1024]
    const float* Wk = (const float*)d_in[2];
    const float* Wv = (const float*)d_in[3];
    float* out = (float*)d_out;                // [4,4096,1024] fp32

    const long long NTOK = 16384LL * 1024LL;
    f16* k  = (f16*)d_ws;                      // 32 MB
    f16* vT = k + NTOK;                        // 32 MB
    f16* q  = (f16*)d_out;                     // interleaved, row stride 2048 halfs

    proj_gemm<<<dim3(128, 8), 256, 0, stream>>>(x, Wq, q, 2048);
    proj_gemm<<<dim3(128, 8), 256, 0, stream>>>(x, Wk, k, 1024);
    proj_gemm<<<dim3(8, 128), 256, 0, stream>>>(Wv, x, vT, 16384);

    flash_attn<<<dim3(256), 512, 0, stream>>>(q, k, vT, out);
}

// Round 5
// 1096.881 us; speedup vs baseline: 1.0860x; 1.0860x over previous
//
#include <hip/hip_runtime.h>
#include <hip/hip_bf16.h>

typedef _Float16 f16;
typedef _Float16 f16x4 __attribute__((ext_vector_type(4)));
typedef _Float16 f16x8 __attribute__((ext_vector_type(8)));
typedef float f32x4 __attribute__((ext_vector_type(4)));

__device__ __forceinline__ void gload16(const void* g, void* l) {
    __builtin_amdgcn_global_load_lds(
        (const __attribute__((address_space(1))) void*)g,
        (__attribute__((address_space(3))) void*)l, 16, 0, 0);
}

// ---------------------------------------------------------------------------
// BT-GEMM (unchanged): C[m][n] = sum_k A[m][k]*B[n][k], fp32 in, f16 out.
// ---------------------------------------------------------------------------
__global__ __launch_bounds__(256) void proj_gemm(
    const float* __restrict__ A, const float* __restrict__ B,
    f16* __restrict__ C, int ldc)
{
    constexpr int K = 1024, BK = 64;
    __shared__ f16 sA[128 * BK];
    __shared__ f16 sB[128 * BK];
    const int tid = threadIdx.x;
    const int lane = tid & 63, wid = tid >> 6;
    const int wr = wid >> 1, wc = wid & 1;
    const int bm = blockIdx.x * 128, bn = blockIdx.y * 128;

    f32x4 acc[4][4] = {};

    for (int kt = 0; kt < K; kt += BK) {
        __syncthreads();
        {
            const int r0 = tid >> 4;
            const int c4 = (tid & 15) << 2;
#pragma unroll
            for (int p = 0; p < 8; ++p) {
                const int row = (p << 4) + r0;
                const float4 av = *(const float4*)(A + (size_t)(bm + row) * K + kt + c4);
                const float4 bv = *(const float4*)(B + (size_t)(bn + row) * K + kt + c4);
                const int sc = c4 ^ ((row & 7) << 3);
                f16x4 ah = { (f16)av.x, (f16)av.y, (f16)av.z, (f16)av.w };
                f16x4 bh = { (f16)bv.x, (f16)bv.y, (f16)bv.z, (f16)bv.w };
                *(f16x4*)(&sA[(row << 6) + sc]) = ah;
                *(f16x4*)(&sB[(row << 6) + sc]) = bh;
            }
        }
        __syncthreads();
#pragma unroll
        for (int ks = 0; ks < 2; ++ks) {
            const int kk = ks * 32 + (lane >> 4) * 8;
            f16x8 a[4], b[4];
#pragma unroll
            for (int i = 0; i < 4; ++i) {
                const int ra = wr * 64 + i * 16 + (lane & 15);
                a[i] = *(const f16x8*)(&sA[(ra << 6) + (kk ^ ((ra & 7) << 3))]);
                const int rb = wc * 64 + i * 16 + (lane & 15);
                b[i] = *(const f16x8*)(&sB[(rb << 6) + (kk ^ ((rb & 7) << 3))]);
            }
#pragma unroll
            for (int i = 0; i < 4; ++i)
#pragma unroll
                for (int j = 0; j < 4; ++j)
                    acc[i][j] = __builtin_amdgcn_mfma_f32_16x16x32_f16(a[i], b[j], acc[i][j], 0, 0, 0);
        }
    }
#pragma unroll
    for (int i = 0; i < 4; ++i)
#pragma unroll
        for (int j = 0; j < 4; ++j)
#pragma unroll
            for (int r = 0; r < 4; ++r) {
                const int row = bm + wr * 64 + i * 16 + (lane >> 4) * 4 + r;
                const int col = bn + wc * 64 + j * 16 + (lane & 15);
                C[(size_t)row * ldc + col] = (f16)acc[i][j][r];
            }
}

// ---------------------------------------------------------------------------
// Flash attention v3: counted-vmcnt chunk pipeline (T3+T4) + setprio (T5).
// Per chunk: stage(ci+1) -> vmcnt(6) [c's loads done, c+1's stay in flight
// ACROSS the barrier] -> s_barrier -> MFMA(c) -> s_barrier. Never vmcnt(0)
// in the main loop (only at the very last chunk).
// Q interleaved in d_out (row stride 2048 halfs); Q/out alias -> no restrict.
// ---------------------------------------------------------------------------
__global__ __launch_bounds__(512, 2) void flash_attn(
    const f16* Q, const f16* __restrict__ Km,
    const f16* __restrict__ VT, float* out)
{
    constexpr int D = 1024, N = 4096, Bq = 64, Bk = 128, DC = 128, NT = N / Bk;
    constexpr int QSTR = 2048;
    __shared__ f16 sQ[2][Bq * DC];      // 2 x 16 KB
    __shared__ f16 sK[2][Bk * DC];      // 2 x 32 KB
    __shared__ float sS[Bq * Bk];       // 32 KB
    __shared__ f16 sP[Bq * Bk];         // 16 KB
    __shared__ float sm[Bq], sl[Bq], sscale[Bq];

    const int tid = threadIdx.x, lane = tid & 63, wid = tid >> 6;
    const int bi = blockIdx.x;
    const int xcd = bi & 7;
    const int b = xcd >> 1;
    const int qb = ((bi >> 3) << 1) | (xcd & 1);

    const size_t kbase = (size_t)b * N * D;
    const size_t vtok = (size_t)b * N;

    const int lq = lane >> 4;
    const int swv = ((((wid & 1) << 2) | lq) & 7) << 3;
    const int colsw = ((lane & 15) << 3) ^ swv;
    const size_t qrow0 = (size_t)b * N + (size_t)qb * Bq;
    const size_t qoff0 = (qrow0 + wid * 4 + lq) * QSTR + colsw;
    const size_t qoff1 = (qrow0 + (wid + 8) * 4 + lq) * QSTR + colsw;
    const size_t koff0 = kbase + (size_t)(wid * 4 + lq) * D + colsw;

    if (tid < Bq) { sm[tid] = -1e30f; sl[tid] = 0.0f; }

    f32x4 acc[4][8] = {};
    const int qf = wid & 3, kh = wid >> 2;

    auto stage = [&](int ci) {
        const int kt2 = ci >> 3, dc2 = ci & 7, bsel = ci & 1;
        const int dco = dc2 << 7;
        f16* qd = &sQ[bsel][wid << 9];
        gload16(Q + qoff0 + dco, qd);
        gload16(Q + qoff1 + dco, qd + 4096);
        const size_t kof = koff0 + ((size_t)kt2 << 17) + dco;
        f16* kd = &sK[bsel][wid << 9];
        gload16(Km + kof,          kd);
        gload16(Km + kof + 32768,  kd + 4096);
        gload16(Km + kof + 65536,  kd + 8192);
        gload16(Km + kof + 98304,  kd + 12288);
    };

    stage(0);
    __syncthreads();

    for (int kt = 0; kt < NT; ++kt) {
        f32x4 accs[4] = {};
        // ---- QK^T over 8 d-chunks, counted-vmcnt pipeline ----
        for (int dc = 0; dc < 8; ++dc) {
            const int ci = kt * 8 + dc;
            if (ci + 1 < NT * 8) {
                stage(ci + 1);
                asm volatile("s_waitcnt vmcnt(6)" ::: "memory");
            } else {
                asm volatile("s_waitcnt vmcnt(0)" ::: "memory");
            }
            __builtin_amdgcn_s_barrier();
            const f16* bq = sQ[dc & 1];
            const f16* bk = sK[dc & 1];
            __builtin_amdgcn_s_setprio(1);
#pragma unroll
            for (int ks = 0; ks < 4; ++ks) {
                const int kk = ks * 32 + (lane >> 4) * 8;
                const int ra = qf * 16 + (lane & 15);
                f16x8 a = *(const f16x8*)(bq + ra * DC + (kk ^ ((ra & 7) << 3)));
#pragma unroll
                for (int f = 0; f < 4; ++f) {
                    const int rb = (kh * 4 + f) * 16 + (lane & 15);
                    f16x8 bb = *(const f16x8*)(bk + rb * DC + (kk ^ ((rb & 7) << 3)));
                    accs[f] = __builtin_amdgcn_mfma_f32_16x16x32_f16(a, bb, accs[f], 0, 0, 0);
                }
            }
            __builtin_amdgcn_s_setprio(0);
            __builtin_amdgcn_s_barrier();
        }
        // ---- write S tile (swizzled; rows stride 4 -> (row>>2)&7 granule) ----
#pragma unroll
        for (int f = 0; f < 4; ++f)
#pragma unroll
            for (int r = 0; r < 4; ++r) {
                const int row = qf * 16 + (lane >> 4) * 4 + r;
                const int col = (kh * 4 + f) * 16 + (lane & 15);
                sS[row * Bk + (col ^ (((row >> 2) & 7) << 3))] = accs[f][r];
            }
        __syncthreads();
        // ---- online softmax: wave owns rows wid*8..+8, 8 lanes/row ----
        {
            const int row = wid * 8 + (lane >> 3);
            const int c0 = (lane & 7) << 4;
            const int sw32 = ((row >> 2) & 7) << 3;
            float v[16];
#pragma unroll
            for (int u = 0; u < 4; ++u) {
                float4 t = *(const float4*)(&sS[row * Bk + ((c0 + u * 4) ^ sw32)]);
                v[u * 4 + 0] = t.x; v[u * 4 + 1] = t.y; v[u * 4 + 2] = t.z; v[u * 4 + 3] = t.w;
            }
            float tmax = v[0];
#pragma unroll
            for (int j = 1; j < 16; ++j) tmax = fmaxf(tmax, v[j]);
#pragma unroll
            for (int m = 1; m <= 4; m <<= 1) tmax = fmaxf(tmax, __shfl_xor(tmax, m));
            const float mold = sm[row];
            const float mnew = fmaxf(mold, tmax);
            float ps = 0.f;
#pragma unroll
            for (int j = 0; j < 16; ++j) { v[j] = __expf(v[j] - mnew); ps += v[j]; }
#pragma unroll
            for (int m = 1; m <= 4; m <<= 1) ps += __shfl_xor(ps, m);
            const float scl = __expf(mold - mnew);
            if ((lane & 7) == 0) {
                sm[row] = mnew;
                sl[row] = sl[row] * scl + ps;
                sscale[row] = scl;
            }
            const int swh = (row & 7) << 3;
            f16x8 p0, p1;
#pragma unroll
            for (int j = 0; j < 8; ++j) { p0[j] = (f16)v[j]; p1[j] = (f16)v[8 + j]; }
            *(f16x8*)(&sP[row * Bk + (c0 ^ swh)]) = p0;
            *(f16x8*)(&sP[row * Bk + ((c0 + 8) ^ swh)]) = p1;
        }
        __syncthreads();
        // ---- rescale accumulator + PV ----
        float scl4[4][4];
#pragma unroll
        for (int i = 0; i < 4; ++i)
#pragma unroll
            for (int r = 0; r < 4; ++r)
                scl4[i][r] = sscale[i * 16 + (lane >> 4) * 4 + r];
#pragma unroll
        for (int i = 0; i < 4; ++i)
#pragma unroll
            for (int j = 0; j < 8; ++j)
#pragma unroll
                for (int r = 0; r < 4; ++r) acc[i][j][r] *= scl4[i][r];
        const size_t tok0 = vtok + (size_t)kt * Bk;
#pragma unroll
        for (int ks = 0; ks < 4; ++ks) {
            const int kk = ks * 32 + (lane >> 4) * 8;
            f16x8 a[4];
#pragma unroll
            for (int i = 0; i < 4; ++i) {
                const int ra = i * 16 + (lane & 15);
                a[i] = *(const f16x8*)(&sP[ra * Bk + (kk ^ ((ra & 7) << 3))]);
            }
#pragma unroll
            for (int j = 0; j < 8; ++j) {
                const int dcol = wid * 128 + j * 16 + (lane & 15);
                const f16x8 bb = *(const f16x8*)(VT + (size_t)dcol * 16384 + tok0 + kk);
#pragma unroll
                for (int i = 0; i < 4; ++i)
                    acc[i][j] = __builtin_amdgcn_mfma_f32_16x16x32_f16(a[i], bb, acc[i][j], 0, 0, 0);
            }
        }
        // next writes to sP/sS are >2 barriers away -> no extra barrier here
    }
    // ---- epilogue: att = acc / (32 * l) ----
#pragma unroll
    for (int i = 0; i < 4; ++i) {
        float inv[4];
#pragma unroll
        for (int r = 0; r < 4; ++r)
            inv[r] = 1.0f / (sl[i * 16 + (lane >> 4) * 4 + r] * 32.0f);
#pragma unroll
        for (int j = 0; j < 8; ++j) {
            const int dcol = wid * 128 + j * 16 + (lane & 15);
#pragma unroll
            for (int r = 0; r < 4; ++r) {
                const int row = i * 16 + (lane >> 4) * 4 + r;
                out[((size_t)b * N + (size_t)qb * Bq + row) * D + dcol] = acc[i][j][r] * inv[r];
            }
        }
    }
}

extern "C" void kernel_launch(void* const* d_in, const int* in_sizes, int n_in,
                              void* d_out, int out_size, void* d_ws, size_t ws_size,
                              hipStream_t stream) {
    const float* x  = (const float*)d_in[0];   // [4,4096,1024]
    const float* Wq = (const float*)d_in[1];   // [1024,1024]
    const float* Wk = (const float*)d_in[2];
    const float* Wv = (const float*)d_in[3];
    float* out = (float*)d_out;                // [4,4096,1024] fp32

    const long long NTOK = 16384LL * 1024LL;
    f16* k  = (f16*)d_ws;                      // 32 MB
    f16* vT = k + NTOK;                        // 32 MB
    f16* q  = (f16*)d_out;                     // interleaved, row stride 2048 halfs

    proj_gemm<<<dim3(128, 8), 256, 0, stream>>>(x, Wq, q, 2048);
    proj_gemm<<<dim3(128, 8), 256, 0, stream>>>(x, Wk, k, 1024);
    proj_gemm<<<dim3(8, 128), 256, 0, stream>>>(Wv, x, vT, 16384);

    flash_attn<<<dim3(256), 512, 0, stream>>>(q, k, vT, out);
}

// Round 6
// 1033.044 us; speedup vs baseline: 1.1531x; 1.0618x over previous
//
#include <hip/hip_runtime.h>
#include <hip/hip_bf16.h>

typedef _Float16 f16;
typedef _Float16 f16x4 __attribute__((ext_vector_type(4)));
typedef _Float16 f16x8 __attribute__((ext_vector_type(8)));
typedef float f32x4 __attribute__((ext_vector_type(4)));

__device__ __forceinline__ void gload16(const void* g, void* l) {
    __builtin_amdgcn_global_load_lds(
        (const __attribute__((address_space(1))) void*)g,
        (__attribute__((address_space(3))) void*)l, 16, 0, 0);
}

// ---------------------------------------------------------------------------
// BT-GEMM: C[m][n] = scale * sum_k A[m][k]*B[n][k].
// Tile 128x128, BK=64, 4 waves (2x2), 16x16x32 f16 MFMA.
// F16IN: A,B f16, staged via global_load_lds (pre-swizzled source, linear LDS).
// !F16IN: A,B f32, staged via float4 loads + f16 convert.
// F16OUT: C f16, else C f32 (scaled).
// LDS[row][slot] holds global col (slot ^ (row&7))*8..+8; reads use
// kk ^ ((row&7)<<3) -- same involution both paths.
// ---------------------------------------------------------------------------
template<bool F16IN, bool F16OUT>
__global__ __launch_bounds__(256) void gemm_bt(
    const void* __restrict__ Av, const void* __restrict__ Bv, void* __restrict__ Cv,
    int K, int lda, int ldb, int ldc, float scale)
{
    __shared__ f16 sA[128 * 64];
    __shared__ f16 sB[128 * 64];
    const int tid = threadIdx.x, lane = tid & 63, wid = tid >> 6;
    const int wr = wid >> 1, wc = wid & 1;
    const int bm = blockIdx.x * 128, bn = blockIdx.y * 128;

    f32x4 acc[4][4] = {};

    for (int kt = 0; kt < K; kt += 64) {
        __syncthreads();
        if constexpr (F16IN) {
            const f16* A = (const f16*)Av;
            const f16* B = (const f16*)Bv;
            const int rsub = lane >> 3;                    // 0..7 rows within 8-row stripe
            const int csw = ((lane & 7) ^ rsub) << 3;      // pre-swizzled source col
#pragma unroll
            for (int i = 0; i < 4; ++i) {
                const int rb = (wid * 4 + i) * 8;          // 8-row stripe base
                gload16(A + (size_t)(bm + rb + rsub) * lda + kt + csw, &sA[rb * 64]);
                gload16(B + (size_t)(bn + rb + rsub) * ldb + kt + csw, &sB[rb * 64]);
            }
        } else {
            const float* A = (const float*)Av;
            const float* B = (const float*)Bv;
            const int r0 = tid >> 4;
            const int c4 = (tid & 15) << 2;
#pragma unroll
            for (int p = 0; p < 8; ++p) {
                const int row = (p << 4) + r0;
                const float4 av = *(const float4*)(A + (size_t)(bm + row) * lda + kt + c4);
                const float4 bv = *(const float4*)(B + (size_t)(bn + row) * ldb + kt + c4);
                const int sc = c4 ^ ((row & 7) << 3);
                f16x4 ah = { (f16)av.x, (f16)av.y, (f16)av.z, (f16)av.w };
                f16x4 bh = { (f16)bv.x, (f16)bv.y, (f16)bv.z, (f16)bv.w };
                *(f16x4*)(&sA[(row << 6) + sc]) = ah;
                *(f16x4*)(&sB[(row << 6) + sc]) = bh;
            }
        }
        __syncthreads();   // drains vmcnt (global_load_lds) / lgkmcnt before reads
#pragma unroll
        for (int ks = 0; ks < 2; ++ks) {
            const int kk = ks * 32 + (lane >> 4) * 8;
            f16x8 a[4], b[4];
#pragma unroll
            for (int i = 0; i < 4; ++i) {
                const int ra = wr * 64 + i * 16 + (lane & 15);
                a[i] = *(const f16x8*)(&sA[(ra << 6) + (kk ^ ((ra & 7) << 3))]);
                const int rb2 = wc * 64 + i * 16 + (lane & 15);
                b[i] = *(const f16x8*)(&sB[(rb2 << 6) + (kk ^ ((rb2 & 7) << 3))]);
            }
#pragma unroll
            for (int i = 0; i < 4; ++i)
#pragma unroll
                for (int j = 0; j < 4; ++j)
                    acc[i][j] = __builtin_amdgcn_mfma_f32_16x16x32_f16(a[i], b[j], acc[i][j], 0, 0, 0);
        }
    }
    // epilogue: C/D frag col=lane&15, row=(lane>>4)*4+r
#pragma unroll
    for (int i = 0; i < 4; ++i)
#pragma unroll
        for (int j = 0; j < 4; ++j)
#pragma unroll
            for (int r = 0; r < 4; ++r) {
                const int row = bm + wr * 64 + i * 16 + (lane >> 4) * 4 + r;
                const int col = bn + wc * 64 + j * 16 + (lane & 15);
                if constexpr (F16OUT)
                    ((f16*)Cv)[(size_t)row * ldc + col] = (f16)acc[i][j][r];
                else
                    ((float*)Cv)[(size_t)row * ldc + col] = acc[i][j][r] * scale;
            }
}

// ---------------------------------------------------------------------------
// Row softmax: one wave per 4096-f32 row, full row in regs, normalized f16 out.
// ---------------------------------------------------------------------------
__global__ __launch_bounds__(256) void softmax_rows(
    const float* __restrict__ S, f16* __restrict__ P)
{
    const int lane = threadIdx.x & 63, wid = threadIdx.x >> 6;
    const int row = blockIdx.x * 4 + wid;
    const float* src = S + (size_t)row * 4096;
    float4 v[16];
#pragma unroll
    for (int u = 0; u < 16; ++u)
        v[u] = *(const float4*)(src + u * 256 + lane * 4);
    float m = -1e30f;
#pragma unroll
    for (int u = 0; u < 16; ++u)
        m = fmaxf(m, fmaxf(fmaxf(v[u].x, v[u].y), fmaxf(v[u].z, v[u].w)));
#pragma unroll
    for (int msk = 1; msk <= 32; msk <<= 1) m = fmaxf(m, __shfl_xor(m, msk));
    float s = 0.f;
#pragma unroll
    for (int u = 0; u < 16; ++u) {
        v[u].x = __expf(v[u].x - m); v[u].y = __expf(v[u].y - m);
        v[u].z = __expf(v[u].z - m); v[u].w = __expf(v[u].w - m);
        s += (v[u].x + v[u].y) + (v[u].z + v[u].w);
    }
#pragma unroll
    for (int msk = 1; msk <= 32; msk <<= 1) s += __shfl_xor(s, msk);
    const float inv = 1.0f / s;
    f16* dst = P + (size_t)row * 4096;
#pragma unroll
    for (int u = 0; u < 16; ++u) {
        f16x4 p = { (f16)(v[u].x * inv), (f16)(v[u].y * inv),
                    (f16)(v[u].z * inv), (f16)(v[u].w * inv) };
        *(f16x4*)(dst + u * 256 + lane * 4) = p;
    }
}

// ---------------------------------------------------------------------------
// Pipeline (per batch b): vT_b = Wv x_b^T; for qq in 0..3: S_q = q_quarter k_b^T,
// softmax -> P quarter (compact); then att_b = (P/32) vT_b^T.
// d_out: token t: halfs [t*2048,+1024)=q_t, [+1024,+2048)=k_t. PV_b overwrites
// exactly batch b's q/k slots, all consumed by then.
// ws (56 MB used): [P 32MB][S_q f32 16MB][vT_b 8MB].
// ---------------------------------------------------------------------------
extern "C" void kernel_launch(void* const* d_in, const int* in_sizes, int n_in,
                              void* d_out, int out_size, void* d_ws, size_t ws_size,
                              hipStream_t stream) {
    const float* x  = (const float*)d_in[0];   // [4,4096,1024]
    const float* Wq = (const float*)d_in[1];   // [1024,1024]
    const float* Wk = (const float*)d_in[2];
    const float* Wv = (const float*)d_in[3];
    float* out = (float*)d_out;                // [4,4096,1024] fp32

    f16*   qk  = (f16*)d_out;                          // q even slots, k odd slots
    f16*   P   = (f16*)d_ws;                           // 32 MB, compact lda=4096
    float* Sq  = (float*)((char*)d_ws + (32 << 20));   // 16 MB f32, 1024x4096
    f16*   vTb = (f16*)((char*)d_ws + (48 << 20));     // 8 MB, 1024x4096

    // projections: q = x Wq^T, k = x Wk^T (f32-staged, f16 out, interleaved)
    gemm_bt<false, true><<<dim3(128, 8), 256, 0, stream>>>(x, Wq, qk,        1024, 1024, 1024, 2048, 1.f);
    gemm_bt<false, true><<<dim3(128, 8), 256, 0, stream>>>(x, Wk, qk + 1024, 1024, 1024, 1024, 2048, 1.f);

    for (int b = 0; b < 4; ++b) {
        // vT_b[d][t'] = sum_e Wv[d][e] x_b[t'][e]
        gemm_bt<false, true><<<dim3(8, 32), 256, 0, stream>>>(
            Wv, x + (size_t)b * 4096 * 1024, vTb, 1024, 1024, 1024, 4096, 1.f);
        for (int qq = 0; qq < 4; ++qq) {
            // S_q[m][n] = q[b,qq*1024+m] . k[b,n]
            gemm_bt<true, false><<<dim3(8, 32), 256, 0, stream>>>(
                qk + (size_t)(b * 4096 + qq * 1024) * 2048,
                qk + 1024 + (size_t)b * 4096 * 2048,
                Sq, 1024, 2048, 2048, 4096, 1.f);
            softmax_rows<<<256, 256, 0, stream>>>(Sq, P + (size_t)qq * 1024 * 4096);
        }
        // att_b = (P . vT_b^T) / 32
        gemm_bt<true, false><<<dim3(32, 8), 256, 0, stream>>>(
            P, vTb, out + (size_t)b * 4096 * 1024, 4096, 4096, 4096, 1024, 1.f / 32.f);
    }
}

// Round 7
// 683.084 us; speedup vs baseline: 1.7438x; 1.5123x over previous
//
#include <hip/hip_runtime.h>
#include <hip/hip_bf16.h>

typedef _Float16 f16;
typedef _Float16 f16x4 __attribute__((ext_vector_type(4)));
typedef _Float16 f16x8 __attribute__((ext_vector_type(8)));
typedef float f32x4 __attribute__((ext_vector_type(4)));

__device__ __forceinline__ void gload16(const void* g, void* l) {
    __builtin_amdgcn_global_load_lds(
        (const __attribute__((address_space(1))) void*)g,
        (__attribute__((address_space(3))) void*)l, 16, 0, 0);
}

// ---------------------------------------------------------------------------
// BT-GEMM: C[m][n] = scale * sum_k A[m][k]*B[n][k]. Tile 128x128, BK=64,
// 4 waves (2x2), 16x16x32 f16 MFMA.
// F16IN: f16 inputs staged via global_load_lds (pre-swizzled source).
// PIPE (requires F16IN): double-buffered LDS, stage(t+1) issued before
//   compute(t), drained by vmcnt(0) AFTER compute -> HBM latency hidden.
// ---------------------------------------------------------------------------
template<bool F16IN, bool F16OUT, bool PIPE>
__global__ __launch_bounds__(256) void gemm_bt(
    const void* __restrict__ Av, const void* __restrict__ Bv, void* __restrict__ Cv,
    int K, int lda, int ldb, int ldc, float scale)
{
    constexpr int NB = PIPE ? 2 : 1;
    __shared__ f16 sA[NB][128 * 64];
    __shared__ f16 sB[NB][128 * 64];
    const int tid = threadIdx.x, lane = tid & 63, wid = tid >> 6;
    const int wr = wid >> 1, wc = wid & 1;
    const int bm = blockIdx.x * 128, bn = blockIdx.y * 128;

    f32x4 acc[4][4] = {};

    auto stage16 = [&](int kt, int bsel) {
        const f16* A = (const f16*)Av;
        const f16* B = (const f16*)Bv;
        const int rsub = lane >> 3;                 // row within 8-row stripe
        const int csw = ((lane & 7) ^ rsub) << 3;   // pre-swizzled source col
#pragma unroll
        for (int i = 0; i < 4; ++i) {
            const int rb = (wid * 4 + i) * 8;
            gload16(A + (size_t)(bm + rb + rsub) * lda + kt + csw, &sA[bsel][rb * 64]);
            gload16(B + (size_t)(bn + rb + rsub) * ldb + kt + csw, &sB[bsel][rb * 64]);
        }
    };

    auto compute = [&](int bsel) {
#pragma unroll
        for (int ks = 0; ks < 2; ++ks) {
            const int kk = ks * 32 + (lane >> 4) * 8;
            f16x8 a[4], b[4];
#pragma unroll
            for (int i = 0; i < 4; ++i) {
                const int ra = wr * 64 + i * 16 + (lane & 15);
                a[i] = *(const f16x8*)(&sA[bsel][(ra << 6) + (kk ^ ((ra & 7) << 3))]);
                const int rb2 = wc * 64 + i * 16 + (lane & 15);
                b[i] = *(const f16x8*)(&sB[bsel][(rb2 << 6) + (kk ^ ((rb2 & 7) << 3))]);
            }
#pragma unroll
            for (int i = 0; i < 4; ++i)
#pragma unroll
                for (int j = 0; j < 4; ++j)
                    acc[i][j] = __builtin_amdgcn_mfma_f32_16x16x32_f16(a[i], b[j], acc[i][j], 0, 0, 0);
        }
    };

    if constexpr (PIPE) {
        static_assert(F16IN, "PIPE requires f16 inputs");
        stage16(0, 0);
        asm volatile("s_waitcnt vmcnt(0)" ::: "memory");
        __syncthreads();
        const int NT2 = K >> 6;
        for (int t = 0; t < NT2; ++t) {
            if (t + 1 < NT2) stage16((t + 1) << 6, (t + 1) & 1);
            compute(t & 1);
            asm volatile("s_waitcnt vmcnt(0)" ::: "memory");   // t+1 landed (hidden under compute)
            __builtin_amdgcn_s_barrier();                       // also protects WAR on buf t&1
        }
    } else {
        for (int kt = 0; kt < K; kt += 64) {
            __syncthreads();
            if constexpr (F16IN) {
                stage16(kt, 0);
            } else {
                const float* A = (const float*)Av;
                const float* B = (const float*)Bv;
                const int r0 = tid >> 4;
                const int c4 = (tid & 15) << 2;
#pragma unroll
                for (int p = 0; p < 8; ++p) {
                    const int row = (p << 4) + r0;
                    const float4 av = *(const float4*)(A + (size_t)(bm + row) * lda + kt + c4);
                    const float4 bv = *(const float4*)(B + (size_t)(bn + row) * ldb + kt + c4);
                    const int sc = c4 ^ ((row & 7) << 3);
                    f16x4 ah = { (f16)av.x, (f16)av.y, (f16)av.z, (f16)av.w };
                    f16x4 bh = { (f16)bv.x, (f16)bv.y, (f16)bv.z, (f16)bv.w };
                    *(f16x4*)(&sA[0][(row << 6) + sc]) = ah;
                    *(f16x4*)(&sB[0][(row << 6) + sc]) = bh;
                }
            }
            __syncthreads();
            compute(0);
        }
    }
    // epilogue: C/D frag col=lane&15, row=(lane>>4)*4+r
#pragma unroll
    for (int i = 0; i < 4; ++i)
#pragma unroll
        for (int j = 0; j < 4; ++j)
#pragma unroll
            for (int r = 0; r < 4; ++r) {
                const int row = bm + wr * 64 + i * 16 + (lane >> 4) * 4 + r;
                const int col = bn + wc * 64 + j * 16 + (lane & 15);
                if constexpr (F16OUT)
                    ((f16*)Cv)[(size_t)row * ldc + col] = (f16)acc[i][j][r];
                else
                    ((float*)Cv)[(size_t)row * ldc + col] = acc[i][j][r] * scale;
            }
}

// ---------------------------------------------------------------------------
// f32 -> f16 convert, 8 elems/thread, grid-stride.
// ---------------------------------------------------------------------------
__global__ __launch_bounds__(256) void cvt_f16(
    const float* __restrict__ s, f16* __restrict__ d, int n8)
{
    int i = blockIdx.x * 256 + threadIdx.x;
    const int stride = gridDim.x * 256;
    for (; i < n8; i += stride) {
        const float4 a = ((const float4*)s)[i * 2];
        const float4 b = ((const float4*)s)[i * 2 + 1];
        f16x8 o = { (f16)a.x, (f16)a.y, (f16)a.z, (f16)a.w,
                    (f16)b.x, (f16)b.y, (f16)b.z, (f16)b.w };
        ((f16x8*)d)[i] = o;
    }
}

// ---------------------------------------------------------------------------
// In-place row softmax: reads 4096-f32 row, writes normalized f16 into the
// FIRST 8KB of the same row (P row stride 8192 halfs). One wave per row.
// NO __restrict__: S/P alias, compiler must keep loads before stores.
// ---------------------------------------------------------------------------
__global__ __launch_bounds__(256) void softmax_inplace(float* S)
{
    const int lane = threadIdx.x & 63, wid = threadIdx.x >> 6;
    const int row = blockIdx.x * 4 + wid;
    float* src = S + (size_t)row * 4096;
    float4 v[16];
#pragma unroll
    for (int u = 0; u < 16; ++u)
        v[u] = ((const float4*)src)[u * 64 + lane];
    float m = -1e30f;
#pragma unroll
    for (int u = 0; u < 16; ++u)
        m = fmaxf(m, fmaxf(fmaxf(v[u].x, v[u].y), fmaxf(v[u].z, v[u].w)));
#pragma unroll
    for (int msk = 1; msk <= 32; msk <<= 1) m = fmaxf(m, __shfl_xor(m, msk));
    float s = 0.f;
#pragma unroll
    for (int u = 0; u < 16; ++u) {
        v[u].x = __expf(v[u].x - m); v[u].y = __expf(v[u].y - m);
        v[u].z = __expf(v[u].z - m); v[u].w = __expf(v[u].w - m);
        s += (v[u].x + v[u].y) + (v[u].z + v[u].w);
    }
#pragma unroll
    for (int msk = 1; msk <= 32; msk <<= 1) s += __shfl_xor(s, msk);
    const float inv = 1.0f / s;
    f16* dst = (f16*)S + (size_t)row * 8192;
#pragma unroll
    for (int u = 0; u < 16; ++u) {
        f16x4 p = { (f16)(v[u].x * inv), (f16)(v[u].y * inv),
                    (f16)(v[u].z * inv), (f16)(v[u].w * inv) };
        *(f16x4*)(dst + u * 256 + lane * 4) = p;
    }
}

// ---------------------------------------------------------------------------
// Pipeline:
//   cvt x->xh, Wq->wqh, Wk->wkh          ws[0:36MB] (dead after proj)
//   proj q,k (F16IN)                      -> d_out interleaved (stride 2048)
//   per batch b:
//     QK_b (F16IN, 1024 blocks)           -> S = ws full 64MB f32
//     softmax_inplace                      -> P f16, lda 8192 (first halves)
//     vT_b (F32IN)                         -> second halves of S rows 3072..4095
//     PV_b (F16IN+PIPE)                    -> out_b (overwrites dead q_b,k_b)
// ---------------------------------------------------------------------------
extern "C" void kernel_launch(void* const* d_in, const int* in_sizes, int n_in,
                              void* d_out, int out_size, void* d_ws, size_t ws_size,
                              hipStream_t stream) {
    const float* x  = (const float*)d_in[0];   // [4,4096,1024]
    const float* Wq = (const float*)d_in[1];   // [1024,1024]
    const float* Wk = (const float*)d_in[2];
    const float* Wv = (const float*)d_in[3];
    float* out = (float*)d_out;                // [4,4096,1024] fp32

    f16*   qk  = (f16*)d_out;                  // q even 1KB-slots, k odd
    f16*   xh  = (f16*)d_ws;                   // 32 MB (transient)
    f16*   wqh = xh + 16384LL * 1024;          // 2 MB
    f16*   wkh = wqh + 1024LL * 1024;          // 2 MB
    float* Sf  = (float*)d_ws;                 // 64 MB S (reuses ws)
    f16*   Sh  = (f16*)d_ws;                   // same region as halfs

    cvt_f16<<<1024, 256, 0, stream>>>(x,  xh,  16384 * 1024 / 8);
    cvt_f16<<<512,  256, 0, stream>>>(Wq, wqh, 1024 * 1024 / 8);
    cvt_f16<<<512,  256, 0, stream>>>(Wk, wkh, 1024 * 1024 / 8);

    // projections (F16IN): q = xh Wq^T, k = xh Wk^T
    gemm_bt<true, true, false><<<dim3(128, 8), 256, 0, stream>>>(
        xh, wqh, qk,        1024, 1024, 1024, 2048, 1.f);
    gemm_bt<true, true, false><<<dim3(128, 8), 256, 0, stream>>>(
        xh, wkh, qk + 1024, 1024, 1024, 1024, 2048, 1.f);

    for (int b = 0; b < 4; ++b) {
        const size_t tb = (size_t)b * 4096;
        // S = q_b k_b^T  (full batch, 1024 blocks)
        gemm_bt<true, false, false><<<dim3(32, 32), 256, 0, stream>>>(
            qk + tb * 2048, qk + tb * 2048 + 1024, Sf,
            1024, 2048, 2048, 4096, 1.f);
        // softmax rows in place -> P (lda 8192)
        softmax_inplace<<<1024, 256, 0, stream>>>(Sf);
        // vT_b = Wv x_b^T -> second halves of rows 3072..4095 (ldc 8192)
        gemm_bt<false, true, false><<<dim3(8, 32), 256, 0, stream>>>(
            Wv, x + tb * 1024, Sh + 3072LL * 8192 + 4096,
            1024, 1024, 1024, 8192, 1.f);
        // att_b = (P vT^T) / 32  (PIPE: dbuf + counted drain)
        gemm_bt<true, false, true><<<dim3(32, 8), 256, 0, stream>>>(
            Sh, Sh + 3072LL * 8192 + 4096, out + tb * 1024,
            4096, 8192, 8192, 1024, 1.f / 32.f);
    }
}

// Round 8
// 649.938 us; speedup vs baseline: 1.8327x; 1.0510x over previous
//
#include <hip/hip_runtime.h>
#include <hip/hip_bf16.h>

typedef _Float16 f16;
typedef _Float16 f16x4 __attribute__((ext_vector_type(4)));
typedef _Float16 f16x8 __attribute__((ext_vector_type(8)));
typedef float f32x4 __attribute__((ext_vector_type(4)));

__device__ __forceinline__ void gload16(const void* g, void* l) {
    __builtin_amdgcn_global_load_lds(
        (const __attribute__((address_space(1))) void*)g,
        (__attribute__((address_space(3))) void*)l, 16, 0, 0);
}

#define FENCE asm volatile("" ::: "memory")
#define BARRIER do { FENCE; __builtin_amdgcn_s_barrier(); FENCE; } while (0)

// ===========================================================================
// 8-phase 256x256 BT-GEMM (T2+T3+T4+T5): C[m][n] = scale*sum_k A[m][k]*B[n][k]
// f16 inputs via global_load_lds (pre-swizzled source, linear LDS), BK=64,
// 8 waves (2Mx4N), per-wave 128x64 out. Per K-tile: 4 phases, one C-quadrant
// each; stage next tile's A-halves at ph1, B-halves at ph2 into the other
// buffer; single vmcnt(0) at ph4 (loads then have ~3 phases of cover).
// ===========================================================================
#define PHASE_MFMA(QI, QJ)                                                    \
    __builtin_amdgcn_s_setprio(1);                                            \
    _Pragma("unroll")                                                         \
    for (int ks = 0; ks < 2; ++ks)                                            \
      _Pragma("unroll")                                                       \
      for (int i = 0; i < 4; ++i)                                             \
        _Pragma("unroll")                                                     \
        for (int j = 0; j < 2; ++j)                                           \
          acc[(QI)*4 + i][(QJ)*2 + j] = __builtin_amdgcn_mfma_f32_16x16x32_f16( \
              a[i][ks], b[j][ks], acc[(QI)*4 + i][(QJ)*2 + j], 0, 0, 0);      \
    __builtin_amdgcn_s_setprio(0);

template<bool F16OUT>
__global__ __launch_bounds__(512) void gemm_bt8(
    const f16* __restrict__ A, const f16* __restrict__ B, void* __restrict__ Cv,
    int K, int lda, int ldb, int ldc, float scale, int nbn)
{
    __shared__ f16 sA[2][256 * 64];     // 2 x 32 KB
    __shared__ f16 sB[2][256 * 64];     // 2 x 32 KB  (128 KB total)
    const int tid = threadIdx.x, lane = tid & 63, wid = tid >> 6;
    const int wr = wid >> 2, wc = wid & 3;

    // XCD-aware swizzle (grid is a multiple of 8)
    const int cpx = gridDim.x >> 3;
    const int wg = (blockIdx.x & 7) * cpx + (blockIdx.x >> 3);
    const int bm = (wg / nbn) << 8, bn = (wg % nbn) << 8;

    // staging: lane covers row (8*wid + lane>>3), slot lane&7; source col
    // pre-swizzled by the (row&7) involution; LDS dest linear (wave-uniform
    // base + lane*16B).
    const int rr8 = lane >> 3;
    const int cs  = ((lane & 7) ^ rr8) << 3;
    const int ldsr = wid << 3;

    auto stageA = [&](int kt, int c, int h) {
        const size_t g0 = (size_t)(bm + (h << 7) + ldsr + rr8) * lda + kt + cs;
        gload16(A + g0,                      &sA[c][((h << 7) + ldsr) << 6]);
        gload16(A + g0 + ((size_t)lda << 6), &sA[c][((h << 7) + 64 + ldsr) << 6]);
    };
    auto stageB = [&](int kt, int c, int h) {
        const size_t g0 = (size_t)(bn + (h << 7) + ldsr + rr8) * ldb + kt + cs;
        gload16(B + g0,                      &sB[c][((h << 7) + ldsr) << 6]);
        gload16(B + g0 + ((size_t)ldb << 6), &sB[c][((h << 7) + 64 + ldsr) << 6]);
    };

    f32x4 acc[8][4] = {};
    f16x8 a[4][2], b[2][2];

    auto loadA = [&](int c, int qi) {
#pragma unroll
        for (int i = 0; i < 4; ++i) {
            const int ra = wr * 128 + (qi * 4 + i) * 16 + (lane & 15);
            const int swz = (ra & 7) << 3;
#pragma unroll
            for (int ks = 0; ks < 2; ++ks) {
                const int kk = ks * 32 + (lane >> 4) * 8;
                a[i][ks] = *(const f16x8*)(&sA[c][(ra << 6) + (kk ^ swz)]);
            }
        }
    };
    auto loadB = [&](int c, int qj) {
#pragma unroll
        for (int j = 0; j < 2; ++j) {
            const int rb = wc * 64 + (qj * 2 + j) * 16 + (lane & 15);
            const int swz = (rb & 7) << 3;
#pragma unroll
            for (int ks = 0; ks < 2; ++ks) {
                const int kk = ks * 32 + (lane >> 4) * 8;
                b[j][ks] = *(const f16x8*)(&sB[c][(rb << 6) + (kk ^ swz)]);
            }
        }
    };

    // prologue: stage tile 0 into buf 0, drain once
    stageA(0, 0, 0); stageA(0, 0, 1); stageB(0, 0, 0); stageB(0, 0, 1);
    asm volatile("s_waitcnt vmcnt(0)" ::: "memory");
    BARRIER;

    const int NT = K >> 6;
    for (int g = 0; g < NT; ++g) {
        const int c = g & 1, cn = c ^ 1;
        const int kn = (g + 1) << 6;
        const bool more = (g + 1) < NT;
        // ---- phase 1: quadrant (0,0); stage next A halves ----
        loadA(c, 0); loadB(c, 0);
        if (more) { stageA(kn, cn, 0); stageA(kn, cn, 1); }
        BARRIER; PHASE_MFMA(0, 0); BARRIER;
        // ---- phase 2: quadrant (0,1); stage next B halves ----
        loadB(c, 1);
        if (more) { stageB(kn, cn, 0); stageB(kn, cn, 1); }
        BARRIER; PHASE_MFMA(0, 1); BARRIER;
        // ---- phase 3: quadrant (1,0) ----
        loadA(c, 1); loadB(c, 0);
        BARRIER; PHASE_MFMA(1, 0); BARRIER;
        // ---- phase 4: quadrant (1,1); single per-tile drain ----
        loadB(c, 1);
        asm volatile("s_waitcnt vmcnt(0)" ::: "memory");
        BARRIER; PHASE_MFMA(1, 1); BARRIER;
    }
    // epilogue: C/D frag col=lane&15, row=(lane>>4)*4+r
#pragma unroll
    for (int i = 0; i < 8; ++i)
#pragma unroll
        for (int j = 0; j < 4; ++j)
#pragma unroll
            for (int r = 0; r < 4; ++r) {
                const int row = bm + wr * 128 + i * 16 + ((lane >> 4) << 2) + r;
                const int col = bn + wc * 64 + j * 16 + (lane & 15);
                if constexpr (F16OUT)
                    ((f16*)Cv)[(size_t)row * ldc + col] = (f16)(acc[i][j][r] * scale);
                else
                    ((float*)Cv)[(size_t)row * ldc + col] = acc[i][j][r] * scale;
            }
}

// ===========================================================================
// 128x128 BT-GEMM (round-7 verified) for PV (PIPE) and vT (f32 staging).
// ===========================================================================
template<bool F16IN, bool F16OUT, bool PIPE>
__global__ __launch_bounds__(256) void gemm_bt(
    const void* __restrict__ Av, const void* __restrict__ Bv, void* __restrict__ Cv,
    int K, int lda, int ldb, int ldc, float scale)
{
    constexpr int NB = PIPE ? 2 : 1;
    __shared__ f16 sA[NB][128 * 64];
    __shared__ f16 sB[NB][128 * 64];
    const int tid = threadIdx.x, lane = tid & 63, wid = tid >> 6;
    const int wr = wid >> 1, wc = wid & 1;
    const int bm = blockIdx.x * 128, bn = blockIdx.y * 128;

    f32x4 acc[4][4] = {};

    auto stage16 = [&](int kt, int bsel) {
        const f16* A = (const f16*)Av;
        const f16* B = (const f16*)Bv;
        const int rsub = lane >> 3;
        const int csw = ((lane & 7) ^ rsub) << 3;
#pragma unroll
        for (int i = 0; i < 4; ++i) {
            const int rb = (wid * 4 + i) * 8;
            gload16(A + (size_t)(bm + rb + rsub) * lda + kt + csw, &sA[bsel][rb * 64]);
            gload16(B + (size_t)(bn + rb + rsub) * ldb + kt + csw, &sB[bsel][rb * 64]);
        }
    };

    auto compute = [&](int bsel) {
#pragma unroll
        for (int ks = 0; ks < 2; ++ks) {
            const int kk = ks * 32 + (lane >> 4) * 8;
            f16x8 a[4], b[4];
#pragma unroll
            for (int i = 0; i < 4; ++i) {
                const int ra = wr * 64 + i * 16 + (lane & 15);
                a[i] = *(const f16x8*)(&sA[bsel][(ra << 6) + (kk ^ ((ra & 7) << 3))]);
                const int rb2 = wc * 64 + i * 16 + (lane & 15);
                b[i] = *(const f16x8*)(&sB[bsel][(rb2 << 6) + (kk ^ ((rb2 & 7) << 3))]);
            }
#pragma unroll
            for (int i = 0; i < 4; ++i)
#pragma unroll
                for (int j = 0; j < 4; ++j)
                    acc[i][j] = __builtin_amdgcn_mfma_f32_16x16x32_f16(a[i], b[j], acc[i][j], 0, 0, 0);
        }
    };

    if constexpr (PIPE) {
        static_assert(F16IN, "PIPE requires f16 inputs");
        stage16(0, 0);
        asm volatile("s_waitcnt vmcnt(0)" ::: "memory");
        __syncthreads();
        const int NT2 = K >> 6;
        for (int t = 0; t < NT2; ++t) {
            if (t + 1 < NT2) stage16((t + 1) << 6, (t + 1) & 1);
            compute(t & 1);
            asm volatile("s_waitcnt vmcnt(0)" ::: "memory");
            __builtin_amdgcn_s_barrier();
        }
    } else {
        for (int kt = 0; kt < K; kt += 64) {
            __syncthreads();
            if constexpr (F16IN) {
                stage16(kt, 0);
            } else {
                const float* A = (const float*)Av;
                const float* B = (const float*)Bv;
                const int r0 = tid >> 4;
                const int c4 = (tid & 15) << 2;
#pragma unroll
                for (int p = 0; p < 8; ++p) {
                    const int row = (p << 4) + r0;
                    const float4 av = *(const float4*)(A + (size_t)(bm + row) * lda + kt + c4);
                    const float4 bv = *(const float4*)(B + (size_t)(bn + row) * ldb + kt + c4);
                    const int sc = c4 ^ ((row & 7) << 3);
                    f16x4 ah = { (f16)av.x, (f16)av.y, (f16)av.z, (f16)av.w };
                    f16x4 bh = { (f16)bv.x, (f16)bv.y, (f16)bv.z, (f16)bv.w };
                    *(f16x4*)(&sA[0][(row << 6) + sc]) = ah;
                    *(f16x4*)(&sB[0][(row << 6) + sc]) = bh;
                }
            }
            __syncthreads();
            compute(0);
        }
    }
#pragma unroll
    for (int i = 0; i < 4; ++i)
#pragma unroll
        for (int j = 0; j < 4; ++j)
#pragma unroll
            for (int r = 0; r < 4; ++r) {
                const int row = bm + wr * 64 + i * 16 + (lane >> 4) * 4 + r;
                const int col = bn + wc * 64 + j * 16 + (lane & 15);
                if constexpr (F16OUT)
                    ((f16*)Cv)[(size_t)row * ldc + col] = (f16)acc[i][j][r];
                else
                    ((float*)Cv)[(size_t)row * ldc + col] = acc[i][j][r] * scale;
            }
}

// ---------------------------------------------------------------------------
// f32 -> f16 convert, 8 elems/thread, grid-stride.
// ---------------------------------------------------------------------------
__global__ __launch_bounds__(256) void cvt_f16(
    const float* __restrict__ s, f16* __restrict__ d, int n8)
{
    int i = blockIdx.x * 256 + threadIdx.x;
    const int stride = gridDim.x * 256;
    for (; i < n8; i += stride) {
        const float4 a = ((const float4*)s)[i * 2];
        const float4 b = ((const float4*)s)[i * 2 + 1];
        f16x8 o = { (f16)a.x, (f16)a.y, (f16)a.z, (f16)a.w,
                    (f16)b.x, (f16)b.y, (f16)b.z, (f16)b.w };
        ((f16x8*)d)[i] = o;
    }
}

// ---------------------------------------------------------------------------
// In-place row softmax: reads 4096-f32 row, writes normalized f16 into the
// FIRST 8KB of the same row (P row stride 8192 halfs). One wave per row.
// ---------------------------------------------------------------------------
__global__ __launch_bounds__(256) void softmax_inplace(float* S)
{
    const int lane = threadIdx.x & 63, wid = threadIdx.x >> 6;
    const int row = blockIdx.x * 4 + wid;
    float* src = S + (size_t)row * 4096;
    float4 v[16];
#pragma unroll
    for (int u = 0; u < 16; ++u)
        v[u] = ((const float4*)src)[u * 64 + lane];
    float m = -1e30f;
#pragma unroll
    for (int u = 0; u < 16; ++u)
        m = fmaxf(m, fmaxf(fmaxf(v[u].x, v[u].y), fmaxf(v[u].z, v[u].w)));
#pragma unroll
    for (int msk = 1; msk <= 32; msk <<= 1) m = fmaxf(m, __shfl_xor(m, msk));
    float s = 0.f;
#pragma unroll
    for (int u = 0; u < 16; ++u) {
        v[u].x = __expf(v[u].x - m); v[u].y = __expf(v[u].y - m);
        v[u].z = __expf(v[u].z - m); v[u].w = __expf(v[u].w - m);
        s += (v[u].x + v[u].y) + (v[u].z + v[u].w);
    }
#pragma unroll
    for (int msk = 1; msk <= 32; msk <<= 1) s += __shfl_xor(s, msk);
    const float inv = 1.0f / s;
    f16* dst = (f16*)S + (size_t)row * 8192;
#pragma unroll
    for (int u = 0; u < 16; ++u) {
        f16x4 p = { (f16)(v[u].x * inv), (f16)(v[u].y * inv),
                    (f16)(v[u].z * inv), (f16)(v[u].w * inv) };
        *(f16x4*)(dst + u * 256 + lane * 4) = p;
    }
}

// ---------------------------------------------------------------------------
// Pipeline: cvt -> proj(8-phase) -> per batch { QK(8-phase) -> SM(inplace)
//           -> vT(128²) -> PV(128² PIPE) }.
// ---------------------------------------------------------------------------
extern "C" void kernel_launch(void* const* d_in, const int* in_sizes, int n_in,
                              void* d_out, int out_size, void* d_ws, size_t ws_size,
                              hipStream_t stream) {
    const float* x  = (const float*)d_in[0];   // [4,4096,1024]
    const float* Wq = (const float*)d_in[1];   // [1024,1024]
    const float* Wk = (const float*)d_in[2];
    const float* Wv = (const float*)d_in[3];
    float* out = (float*)d_out;                // [4,4096,1024] fp32

    f16*   qk  = (f16*)d_out;                  // q even 1KB-slots, k odd
    f16*   xh  = (f16*)d_ws;                   // 32 MB (transient)
    f16*   wqh = xh + 16384LL * 1024;          // 2 MB
    f16*   wkh = wqh + 1024LL * 1024;          // 2 MB
    float* Sf  = (float*)d_ws;                 // 64 MB S (reuses ws)
    f16*   Sh  = (f16*)d_ws;

    cvt_f16<<<1024, 256, 0, stream>>>(x,  xh,  16384 * 1024 / 8);
    cvt_f16<<<512,  256, 0, stream>>>(Wq, wqh, 1024 * 1024 / 8);
    cvt_f16<<<512,  256, 0, stream>>>(Wk, wkh, 1024 * 1024 / 8);

    // projections (8-phase 256²): q = xh Wq^T, k = xh Wk^T
    gemm_bt8<true><<<256, 512, 0, stream>>>(xh, wqh, qk,        1024, 1024, 1024, 2048, 1.f, 4);
    gemm_bt8<true><<<256, 512, 0, stream>>>(xh, wkh, qk + 1024, 1024, 1024, 1024, 2048, 1.f, 4);

    for (int b = 0; b < 4; ++b) {
        const size_t tb = (size_t)b * 4096;
        // S = q_b k_b^T  (8-phase 256², 256 blocks)
        gemm_bt8<false><<<256, 512, 0, stream>>>(
            qk + tb * 2048, qk + tb * 2048 + 1024, Sf,
            1024, 2048, 2048, 4096, 1.f, 16);
        // softmax rows in place -> P (lda 8192)
        softmax_inplace<<<1024, 256, 0, stream>>>(Sf);
        // vT_b = Wv x_b^T -> second halves of rows 3072..4095 (ldc 8192)
        gemm_bt<false, true, false><<<dim3(8, 32), 256, 0, stream>>>(
            Wv, x + tb * 1024, Sh + 3072LL * 8192 + 4096,
            1024, 1024, 1024, 8192, 1.f);
        // att_b = (P vT^T) / 32  (128² PIPE)
        gemm_bt<true, false, true><<<dim3(32, 8), 256, 0, stream>>>(
            Sh, Sh + 3072LL * 8192 + 4096, out + tb * 1024,
            4096, 8192, 8192, 1024, 1.f / 32.f);
    }
}